// Round 13
// baseline (168458.984 us; speedup 1.0000x reference)
//
#include <hip/hip_runtime.h>
#include <math.h>

#define T_STEPS 20000
#define RSIZE   2048
#define ISIZE   128
#define NBLK    32
#define NTHR    1024                   // 16 waves/block, 1 block/CU (32 CUs)
#define WPB     (NTHR / 64)            // 16 waves per block
#define NWAVE   (NBLK * WPB)           // 512 waves
#define RPW     4                      // rows per wave (2048 / 512)

// ---- cheap erf: Abramowitz-Stegun 7.1.26, |err| <= 1.5e-7 (abs) ----
__device__ __forceinline__ float erf_approx(float x) {
    float ax = fabsf(x);
    float t  = 1.0f / (1.0f + 0.3275911f * ax);
    float y  = t * (0.254829592f +
               t * (-0.284496736f +
               t * (1.421413741f +
               t * (-1.453152027f +
               t * 1.061405429f))));
    float e  = __expf(-ax * ax);
    float r  = 1.0f - y * e;
    return copysignf(r, x);
}

// ---- AGPR parking (gfx950 unified RF; no MFMA here, AGPRs = free storage).
// VALU cannot source AGPRs on gfx950 — only v_accvgpr_read/write move data.
#define AGPR_W(a, v) asm volatile("v_accvgpr_write_b32 %0, %1" : "=a"(a) : "v"(v))
#define AGPR_R(v, a) asm volatile("v_accvgpr_read_b32 %0, %1" : "=v"(v) : "a"(a))

// ---- device-coherent (L3-serviced) accesses ----
__device__ __forceinline__ unsigned ld_coh_u32(const unsigned* p) {
    unsigned r;
    asm volatile("global_load_dword %0, %1, off sc0 sc1\n\ts_waitcnt vmcnt(0)"
                 : "=&v"(r) : "v"(p) : "memory");
    return r;
}
__device__ __forceinline__ float2 ld_coh_f2(const float* p) {
    float2 r;
    asm volatile("global_load_dwordx2 %0, %1, off sc0 sc1\n\ts_waitcnt vmcnt(0)"
                 : "=&v"(r) : "v"(p) : "memory");
    return r;
}
__device__ __forceinline__ void st_coh_f32(float* p, float v) {
    asm volatile("global_store_dword %0, %1, off sc0 sc1"
                 :: "v"(p), "v"(v) : "memory");
}
__device__ __forceinline__ void st_coh_u32(unsigned* p, unsigned v) {
    asm volatile("global_store_dword %0, %1, off sc0 sc1"
                 :: "v"(p), "v"(v) : "memory");
}

__global__ __launch_bounds__(NTHR, 4) void esn_persistent(
        const float* __restrict__ input,   // [T, 128]
        const float* __restrict__ W_in,    // [2048, 128]
        const float* __restrict__ W_res,   // [2048, 2048]
        float* __restrict__ out,           // [T, 2048] (rows ARE the states)
        unsigned* __restrict__ flags) {    // [32] packed per-BLOCK monotonic
    __shared__ float xbuf[RSIZE];

    const int tid  = threadIdx.x;
    const int lane = tid & 63;
    const int wv   = tid >> 6;
    const int wid  = blockIdx.x * WPB + wv;
    const int r0   = wid * RPW;
    const float invs = 0.022097086912079608f;  // 1/sqrt(2048)

    // ---- load W once, park in AGPRs (row r0+m, lane l: cols c*256+l*4..+3) --
    float a_w[RPW][32];
    float a_wi[RPW][2];
#pragma unroll
    for (int m = 0; m < RPW; ++m) {
        const float* row = W_res + (size_t)(r0 + m) * RSIZE;
#pragma unroll
        for (int c = 0; c < 8; ++c) {
            float4 w = *(const float4*)(row + c * 256 + lane * 4);
            AGPR_W(a_w[m][c * 4 + 0], w.x);
            AGPR_W(a_w[m][c * 4 + 1], w.y);
            AGPR_W(a_w[m][c * 4 + 2], w.z);
            AGPR_W(a_w[m][c * 4 + 3], w.w);
        }
        float2 wiv = *(const float2*)(W_in + (size_t)(r0 + m) * ISIZE + lane * 2);
        AGPR_W(a_wi[m][0], wiv.x);
        AGPR_W(a_wi[m][1], wiv.y);
    }

    for (int t = 0; t < T_STEPS; ++t) {
        // ---- input projection (independent of other blocks) ----
        float2 uv = ((const float2*)(input + (size_t)t * ISIZE))[lane];
        float acc[RPW];
#pragma unroll
        for (int m = 0; m < RPW; ++m) {
            float w0, w1;
            AGPR_R(w0, a_wi[m][0]);
            AGPR_R(w1, a_wi[m][1]);
            acc[m] = fmaf(w0, uv.x, w1 * uv.y);
        }

        // ---- wait for x[t-1]: wave0 polls the 32 packed block-flags ----
        if (t > 0) {
            if (wv == 0) {
                const unsigned want = (unsigned)t;
                const unsigned* pf = flags + (lane & 31);  // one 128B line
                while (true) {
                    unsigned f = ld_coh_u32(pf);
                    if (__all((int)(f >= want))) break;
                    __builtin_amdgcn_s_sleep(1);
                }
            }
            __syncthreads();
            // flags at L3 => producers' coherent value stores are at L3;
            // sc0 sc1 stage loads are L3-serviced => fresh.
            const float* xprev = out + (size_t)(t - 1) * RSIZE;
            ((float2*)xbuf)[tid] = ld_coh_f2(xprev + tid * 2);
        } else {
            ((float2*)xbuf)[tid] = make_float2(0.f, 0.f);
        }
        __syncthreads();

        // ---- frags from LDS ----
        float4 xv[8];
#pragma unroll
        for (int c = 0; c < 8; ++c)
            xv[c] = ((const float4*)xbuf)[c * 64 + lane];
        float xp = xbuf[r0 + (lane & 3)];

        // ---- matvec: W from AGPRs (read+fma), 4 independent chains ----
#pragma unroll
        for (int c = 0; c < 8; ++c) {
#pragma unroll
            for (int m = 0; m < RPW; ++m) {
                float t0, t1, t2, t3;
                AGPR_R(t0, a_w[m][c * 4 + 0]);
                AGPR_R(t1, a_w[m][c * 4 + 1]);
                AGPR_R(t2, a_w[m][c * 4 + 2]);
                AGPR_R(t3, a_w[m][c * 4 + 3]);
                float p0 = fmaf(t0, xv[c].x, acc[m]);
                float p1 = t1 * xv[c].y;
                float p2 = fmaf(t2, xv[c].z, p0);
                float p3 = fmaf(t3, xv[c].w, p1);
                acc[m] = p2 + p3;
            }
        }
#pragma unroll
        for (int m = 0; m < RPW; ++m) {
            float a = acc[m];
#pragma unroll
            for (int off = 32; off > 0; off >>= 1)
                a += __shfl_xor(a, off, 64);
            acc[m] = a;   // all lanes hold all 4 row sums
        }

        // ---- finish 4 rows (lanes 0..3): coherent value stores ----
        if (lane < RPW) {
            float pre = (lane == 0) ? acc[0]
                      : (lane == 1) ? acc[1]
                      : (lane == 2) ? acc[2] : acc[3];
            float xn  = 0.1f * xp + 0.9f * erf_approx(pre) * invs;
            st_coh_f32(out + (size_t)t * RSIZE + r0 + lane, xn);
        }

        // ---- block-level publish (tail proven off critical path, r12) ----
        if (t + 1 < T_STEPS) {
            asm volatile("s_waitcnt vmcnt(0)" ::: "memory");  // drain own stores
            __syncthreads();                                   // all waves done
            if (tid == 0)
                st_coh_u32(flags + blockIdx.x, (unsigned)(t + 1));
        }
    }
}

extern "C" void kernel_launch(void* const* d_in, const int* in_sizes, int n_in,
                              void* d_out, int out_size, void* d_ws,
                              size_t ws_size, hipStream_t stream) {
    const float* input = (const float*)d_in[0];
    const float* W_in  = (const float*)d_in[1];
    const float* W_res = (const float*)d_in[2];
    float*       out   = (float*)d_out;
    unsigned*    flags = (unsigned*)d_ws;   // 32 * 4 B packed

    // flags must be zero at the start of every call (deterministic)
    hipMemsetAsync(flags, 0, NBLK * sizeof(unsigned), stream);

    void* args[] = {(void*)&input, (void*)&W_in, (void*)&W_res,
                    (void*)&out, (void*)&flags};
    hipError_t err = hipLaunchCooperativeKernel(
        (const void*)esn_persistent, dim3(NBLK), dim3(NTHR), args, 0, stream);
    if (err != hipSuccess) {
        // 32 blocks / 256 CUs: trivially co-resident; plain launch fallback
        esn_persistent<<<dim3(NBLK), dim3(NTHR), 0, stream>>>(
            input, W_in, W_res, out, flags);
    }
}